// Round 13
// baseline (745.977 us; speedup 1.0000x reference)
//
#include <hip/hip_runtime.h>
#include <hip/hip_bf16.h>

// Established facts (R3-R12): d_in = setup_inputs() dict order; floats fp32;
// edges int32; output fp32 [20000,128]. R12: 658 us. This round: gemm_all
// drops LDS staging (wave-uniform h reads -> scalar loads; el/er via shfl);
// pull_semw edge loop unrolled x8 (order-preserving).
#define NN 20000
#define RR 3
#define EE 320000
#define FD 128
#define AH 32
#define NP1 (NN + 1)
#define NEG_SLOPE 0.2f

__device__ __forceinline__ int clamp_idx(int v) {
  v = v < 0 ? 0 : v;
  return v < NN ? v : NN - 1;
}
__device__ __forceinline__ float leaky_exp(float e) {
  e = e > 0.f ? e : NEG_SLOPE * e;
  return __expf(e);
}

// ----------------------------- CSR build -----------------------------------
__global__ void csr_count(const int* __restrict__ edg, int* __restrict__ cnt) {
  const int idx = blockIdx.x * blockDim.x + threadIdx.x;
  if (idx >= RR * EE) return;
  const int r = idx / EE, k = idx - r * EE;
  const int dst = clamp_idx(edg[(size_t)r * 2 * EE + EE + k]);
  atomicAdd(&cnt[r * NN + dst], 1);
}

__global__ void csr_scan(const int* __restrict__ cnt, int* __restrict__ starts,
                         int* __restrict__ cursor) {
  __shared__ int part[256];
  const int r = blockIdx.x, t = threadIdx.x;
  const int CH = (NN + 255) / 256;  // 79
  const int lo = t * CH, hi = min(lo + CH, NN);
  int s = 0;
  for (int i = lo; i < hi; ++i) s += cnt[r * NN + i];
  part[t] = s;
  __syncthreads();
  if (t == 0) {
    int run = 0;
    for (int i = 0; i < 256; ++i) { const int v = part[i]; part[i] = run; run += v; }
  }
  __syncthreads();
  int run = part[t];
  for (int i = lo; i < hi; ++i) {
    starts[r * NP1 + i] = run;
    cursor[r * NP1 + i] = run;
    run += cnt[r * NN + i];
  }
  if (t == 255) starts[r * NP1 + NN] = run;
}

__global__ void csr_scatter(const int* __restrict__ edg, int* __restrict__ cursor,
                            int* __restrict__ csrsrc) {
  const int idx = blockIdx.x * blockDim.x + threadIdx.x;
  if (idx >= RR * EE) return;
  const int r = idx / EE, k = idx - r * EE;
  const int src = clamp_idx(edg[(size_t)r * 2 * EE + k]);
  const int dst = clamp_idx(edg[(size_t)r * 2 * EE + EE + k]);
  const int pos = atomicAdd(&cursor[r * NP1 + dst], 1);
  csrsrc[(size_t)r * EE + pos] = src;
}

// ---------------------------------------------------------------------------
// Merged gemm v2: f[r] = h_in @ W[r], el/er fused. Block 128, BN=16 nodes.
// NO LDS: h-tile addresses are wave-uniform (blockIdx/loop-derived) -> the
// compiler emits scalar s_load (SMEM pipe, free broadcast), removing the
// 512 ds_read_b128/thread that made R12's gemm LDS-throughput-bound.
// W reads are lane-coalesced vector loads (L2-resident, 192 KB).
// el/er: wave shuffle reduction (intra-wave, barrier-free).
// ---------------------------------------------------------------------------
#define BN 16
__global__ void gemm_all(const float* __restrict__ hin,  // [N,128]
                         const float* __restrict__ W,    // [3,128,128]
                         const float* __restrict__ al,   // [3,128]
                         const float* __restrict__ ar,   // [3,128]
                         float* __restrict__ f,          // [3,N,128]
                         float* __restrict__ el,         // [3,N,2]
                         float* __restrict__ er) {
  const int blocksPerRel = NN / BN;  // 1250
  const int r = blockIdx.x / blocksPerRel;
  const int n0 = (blockIdx.x % blocksPerRel) * BN;
  const int j = threadIdx.x;  // 0..127

  const float* Wr = W + (size_t)r * FD * FD;
  float acc[BN];
#pragma unroll
  for (int i = 0; i < BN; ++i) acc[i] = 0.f;

  for (int k4 = 0; k4 < FD; k4 += 4) {
    const float w0 = Wr[(size_t)(k4 + 0) * FD + j];
    const float w1 = Wr[(size_t)(k4 + 1) * FD + j];
    const float w2 = Wr[(size_t)(k4 + 2) * FD + j];
    const float w3 = Wr[(size_t)(k4 + 3) * FD + j];
#pragma unroll
    for (int i = 0; i < BN; ++i) {
      // Wave-uniform address -> scalar load (s_load_dwordx4), broadcast free.
      const float4 h4 = *(const float4*)&hin[(size_t)(n0 + i) * FD + k4];
      acc[i] = fmaf(h4.x, w0, fmaf(h4.y, w1, fmaf(h4.z, w2, fmaf(h4.w, w3, acc[i]))));
    }
  }

  const float alv = al[r * FD + j];
  const float arv = ar[r * FD + j];
  const int h = j >> 6;
  const int lane = j & 63;

#pragma unroll
  for (int i = 0; i < BN; ++i) {
    f[((size_t)r * NN + n0 + i) * FD + j] = acc[i];
    float pl = acc[i] * alv;
    float pr = acc[i] * arv;
#pragma unroll
    for (int off = 32; off > 0; off >>= 1) {
      pl += __shfl_down(pl, off, 64);
      pr += __shfl_down(pr, off, 64);
    }
    if (lane == 0) {
      el[((size_t)r * NN + n0 + i) * 2 + h] = pl;
      er[((size_t)r * NN + n0 + i) * 2 + h] = pr;
    }
  }
}

// ---------------------------------------------------------------------------
// Fused pull + semantic-attention logit: one block per (r, dst).
// Edge loop unrolled x8 (p-ascending accumulation order preserved ->
// bitwise-identical z vs R12). The f-row gather is the latency bound.
// ---------------------------------------------------------------------------
__global__ void pull_semw(const int* __restrict__ starts,  // [3,NP1]
                          const int* __restrict__ csrsrc,  // [3,E]
                          const float* __restrict__ el,    // [3,N,2]
                          const float* __restrict__ er,
                          const float* __restrict__ f,     // [3,N,128]
                          const float* __restrict__ b,     // [3,128]
                          int do_relu,
                          const float* __restrict__ aw1,   // [128,32]
                          const float* __restrict__ ab1,   // [32]
                          const float* __restrict__ aw2,   // [32]
                          float* __restrict__ z,           // [3,N,128]
                          float* __restrict__ wv) {        // [3,N]
  __shared__ float lz[FD];
  __shared__ float red[4][AH];
  __shared__ float wcol[AH];
  const int rn = blockIdx.x;
  const int r = rn / NN;
  const int n = rn - r * NN;
  const int j = threadIdx.x;
  const int h = j >> 6;
  const int* st = starts + r * NP1;
  const int* cs = csrsrc + (size_t)r * EE;
  const float* elr = el + (size_t)r * NN * 2;
  const float* fr = f + (size_t)r * NN * FD;
  const int s0 = st[n], s1 = st[n + 1];
  const float ern = er[((size_t)r * NN + n) * 2 + h];

  float acc = 0.f, den = 0.f;
  int p = s0;
  for (; p + 8 <= s1; p += 8) {
    const int i0 = cs[p + 0];
    const int i1 = cs[p + 1];
    const int i2 = cs[p + 2];
    const int i3 = cs[p + 3];
    const int i4 = cs[p + 4];
    const int i5 = cs[p + 5];
    const int i6 = cs[p + 6];
    const int i7 = cs[p + 7];
    const float w0 = leaky_exp(elr[(size_t)i0 * 2 + h] + ern);
    const float w1 = leaky_exp(elr[(size_t)i1 * 2 + h] + ern);
    const float w2 = leaky_exp(elr[(size_t)i2 * 2 + h] + ern);
    const float w3 = leaky_exp(elr[(size_t)i3 * 2 + h] + ern);
    const float w4 = leaky_exp(elr[(size_t)i4 * 2 + h] + ern);
    const float w5 = leaky_exp(elr[(size_t)i5 * 2 + h] + ern);
    const float w6 = leaky_exp(elr[(size_t)i6 * 2 + h] + ern);
    const float w7 = leaky_exp(elr[(size_t)i7 * 2 + h] + ern);
    const float f0 = fr[(size_t)i0 * FD + j];
    const float f1 = fr[(size_t)i1 * FD + j];
    const float f2 = fr[(size_t)i2 * FD + j];
    const float f3 = fr[(size_t)i3 * FD + j];
    const float f4 = fr[(size_t)i4 * FD + j];
    const float f5 = fr[(size_t)i5 * FD + j];
    const float f6 = fr[(size_t)i6 * FD + j];
    const float f7 = fr[(size_t)i7 * FD + j];
    den += w0; acc += w0 * f0;   // strict p-ascending order: bitwise-
    den += w1; acc += w1 * f1;   // identical to the serial loop
    den += w2; acc += w2 * f2;
    den += w3; acc += w3 * f3;
    den += w4; acc += w4 * f4;
    den += w5; acc += w5 * f5;
    den += w6; acc += w6 * f6;
    den += w7; acc += w7 * f7;
  }
  for (; p + 4 <= s1; p += 4) {
    const int i0 = cs[p + 0];
    const int i1 = cs[p + 1];
    const int i2 = cs[p + 2];
    const int i3 = cs[p + 3];
    const float w0 = leaky_exp(elr[(size_t)i0 * 2 + h] + ern);
    const float w1 = leaky_exp(elr[(size_t)i1 * 2 + h] + ern);
    const float w2 = leaky_exp(elr[(size_t)i2 * 2 + h] + ern);
    const float w3 = leaky_exp(elr[(size_t)i3 * 2 + h] + ern);
    const float f0 = fr[(size_t)i0 * FD + j];
    const float f1 = fr[(size_t)i1 * FD + j];
    const float f2 = fr[(size_t)i2 * FD + j];
    const float f3 = fr[(size_t)i3 * FD + j];
    den += w0; acc += w0 * f0;
    den += w1; acc += w1 * f1;
    den += w2; acc += w2 * f2;
    den += w3; acc += w3 * f3;
  }
  for (; p < s1; ++p) {
    const int src = cs[p];
    const float w = leaky_exp(elr[(size_t)src * 2 + h] + ern);
    den += w;
    acc += w * fr[(size_t)src * FD + j];
  }

  float v = acc / fmaxf(den, 1e-9f) + b[r * FD + j];
  if (do_relu) v = fmaxf(v, 0.f);
  z[(size_t)rn * FD + j] = v;

  // ---- fused semantic-attention logit for this (r,n) ----
  lz[j] = v;
  __syncthreads();
  const int col = j & 31;
  const int part = j >> 5;
  float a2 = 0.f;
#pragma unroll
  for (int kk = 0; kk < 32; ++kk) {
    const int k = part * 32 + kk;
    a2 += lz[k] * aw1[(size_t)k * AH + col];
  }
  red[part][col] = a2;
  __syncthreads();
  if (part == 0)
    wcol[col] = tanhf(red[0][col] + red[1][col] + red[2][col] + red[3][col] +
                      ab1[col]) * aw2[col];
  __syncthreads();
  if (j == 0) {
    float w = 0.f;
#pragma unroll
    for (int c = 0; c < AH; ++c) w += wcol[c];
    wv[rn] = w;
  }
}

// Fused reduce + beta: S[r] = sum_n wv[r,n]; beta = softmax(S/N) -> S[4..6]
__global__ void reduce_beta(const float* __restrict__ wv, float* __restrict__ S) {
  __shared__ float p[256];
  const int t = threadIdx.x;
  float tot[RR];
  for (int r = 0; r < RR; ++r) {
    float s = 0.f;
    for (int n = t; n < NN; n += 256) s += wv[(size_t)r * NN + n];
    p[t] = s;
    __syncthreads();
    for (int off = 128; off > 0; off >>= 1) {
      if (t < off) p[t] += p[t + off];
      __syncthreads();
    }
    tot[r] = p[0];
    __syncthreads();
  }
  if (t == 0) {
    S[0] = tot[0]; S[1] = tot[1]; S[2] = tot[2];
    float w0 = tot[0] / (float)NN, w1 = tot[1] / (float)NN, w2 = tot[2] / (float)NN;
    float mx = fmaxf(w0, fmaxf(w1, w2));
    float e0 = __expf(w0 - mx), e1 = __expf(w1 - mx), e2 = __expf(w2 - mx);
    float inv = 1.f / (e0 + e1 + e2);
    S[4] = e0 * inv; S[5] = e1 * inv; S[6] = e2 * inv;
  }
}

__global__ void combine_f32(const float* __restrict__ z,
                            const float* __restrict__ S,
                            float* __restrict__ out) {
  const int idx = blockIdx.x * blockDim.x + threadIdx.x;
  if (idx >= NN * FD) return;
  out[idx] = S[4] * z[idx] + S[5] * z[(size_t)NN * FD + idx] +
             S[6] * z[2 * (size_t)NN * FD + idx];
}

// ------------------- fallback kernels (R10 CSR path, proven) ----------------
__global__ void gemm_el_er(const float* __restrict__ hin,
                           const float* __restrict__ W,
                           const float* __restrict__ al,
                           const float* __restrict__ ar,
                           float* __restrict__ f,
                           float* __restrict__ el,
                           float* __restrict__ er) {
  const int B8 = 8;
  __shared__ float lh[B8 * FD];
  const int j = threadIdx.x;
  const int n0 = blockIdx.x * B8;
#pragma unroll
  for (int i = 0; i < B8; ++i)
    lh[i * FD + j] = hin[(size_t)(n0 + i) * FD + j];
  __syncthreads();
  float acc[B8];
#pragma unroll
  for (int i = 0; i < B8; ++i) acc[i] = 0.f;
  for (int k = 0; k < FD; ++k) {
    const float w = W[(size_t)k * FD + j];
#pragma unroll
    for (int i = 0; i < B8; ++i) acc[i] += lh[i * FD + k] * w;
  }
  const float alv = al[j];
  const float arv = ar[j];
#pragma unroll
  for (int i = 0; i < B8; ++i) f[(size_t)(n0 + i) * FD + j] = acc[i];
  __syncthreads();
#pragma unroll
  for (int i = 0; i < B8; ++i) lh[i * FD + j] = acc[i] * alv;
  __syncthreads();
  if (j < B8 * 2) {
    const int i = j >> 1, h = j & 1;
    const float* p = &lh[i * FD + h * 64];
    float s = 0.f;
    for (int d = 0; d < 64; ++d) s += p[d];
    el[(size_t)(n0 + i) * 2 + h] = s;
  }
  __syncthreads();
#pragma unroll
  for (int i = 0; i < B8; ++i) lh[i * FD + j] = acc[i] * arv;
  __syncthreads();
  if (j < B8 * 2) {
    const int i = j >> 1, h = j & 1;
    const float* p = &lh[i * FD + h * 64];
    float s = 0.f;
    for (int d = 0; d < 64; ++d) s += p[d];
    er[(size_t)(n0 + i) * 2 + h] = s;
  }
}

__global__ void pull_aggr(const int* __restrict__ starts,
                          const int* __restrict__ csrsrc,
                          const float* __restrict__ el,
                          const float* __restrict__ er,
                          const float* __restrict__ f,
                          const float* __restrict__ b,
                          int do_relu,
                          float* __restrict__ z) {
  const int n = blockIdx.x;
  const int j = threadIdx.x;
  const int h = j >> 6;
  const int s0 = starts[n], s1 = starts[n + 1];
  const float ern = er[(size_t)n * 2 + h];
  float acc = 0.f, den = 0.f;
  for (int p = s0; p < s1; ++p) {
    const int src = csrsrc[p];
    const float w = leaky_exp(el[(size_t)src * 2 + h] + ern);
    den += w;
    acc += w * f[(size_t)src * FD + j];
  }
  float v = acc / fmaxf(den, 1e-9f) + b[j];
  if (do_relu) v = fmaxf(v, 0.f);
  z[(size_t)n * FD + j] = v;
}

__global__ void semw_nodes(const float* __restrict__ z,
                           const float* __restrict__ aw1,
                           const float* __restrict__ ab1,
                           const float* __restrict__ aw2,
                           float* __restrict__ wv) {
  __shared__ float lz[2][FD];
  __shared__ float red[2][4][AH];
  __shared__ float wcol[2][AH];
  const int g = threadIdx.x >> 7;
  const int t = threadIdx.x & 127;
  const int pair = blockIdx.x * 2 + g;
  const int n = pair / RR;
  const int r = pair - n * RR;
  lz[g][t] = z[((size_t)r * NN + n) * FD + t];
  __syncthreads();
  const int col = t & 31;
  const int part = t >> 5;
  float acc = 0.f;
#pragma unroll
  for (int kk = 0; kk < 32; ++kk) {
    const int k = part * 32 + kk;
    acc += lz[g][k] * aw1[(size_t)k * AH + col];
  }
  red[g][part][col] = acc;
  __syncthreads();
  if (part == 0) {
    float s = red[g][0][col] + red[g][1][col] + red[g][2][col] + red[g][3][col];
    wcol[g][col] = tanhf(s + ab1[col]) * aw2[col];
  }
  __syncthreads();
  if (t == 0) {
    float w = 0.f;
#pragma unroll
    for (int c = 0; c < AH; ++c) w += wcol[g][c];
    wv[(size_t)r * NN + n] = w;
  }
}

// ---------------------------------------------------------------------------
extern "C" void kernel_launch(void* const* d_in, const int* in_sizes, int n_in,
                              void* d_out, int out_size, void* d_ws, size_t ws_size,
                              hipStream_t stream) {
  const float* x   = (const float*)d_in[0];
  const int*   edg = (const int*)d_in[1];
  const float* W1  = (const float*)d_in[2];
  const float* al1 = (const float*)d_in[3];
  const float* ar1 = (const float*)d_in[4];
  const float* b1  = (const float*)d_in[5];
  const float* W2  = (const float*)d_in[6];
  const float* al2 = (const float*)d_in[7];
  const float* ar2 = (const float*)d_in[8];
  const float* b2  = (const float*)d_in[9];
  const float* aw1 = (const float*)d_in[10];
  const float* ab1 = (const float*)d_in[11];
  const float* aw2 = (const float*)d_in[12];
  const float* bw1 = (const float*)d_in[13];
  const float* bb1 = (const float*)d_in[14];
  const float* bw2 = (const float*)d_in[15];
  float* out = (float*)d_out;

  const size_t need_big = 67200128;  // merged path: 67.2 MB (proven to fit)
  if (ws_size >= need_big) {
    float* S      = (float*)d_ws;                    // 16
    float* wv     = S + 16;                          // RR*NN
    float* el     = wv + (size_t)RR * NN;            // RR*NN*2
    float* er     = el + (size_t)RR * NN * 2;        // RR*NN*2
    float* f      = er + (size_t)RR * NN * 2;        // RR*NN*FD
    float* z      = f + (size_t)RR * NN * FD;        // RR*NN*FD
    int*   cnt    = (int*)(z + (size_t)RR * NN * FD);// RR*NN
    int*   starts = cnt + RR * NN;                   // RR*NP1
    int*   cursor = starts + RR * NP1;               // RR*NP1
    int*   csrsrc = cursor + RR * NP1;               // RR*EE

    hipMemsetAsync(cnt, 0, (size_t)RR * NN * sizeof(int), stream);
    csr_count<<<(RR * EE + 255) / 256, 256, 0, stream>>>(edg, cnt);
    csr_scan<<<RR, 256, 0, stream>>>(cnt, starts, cursor);
    csr_scatter<<<(RR * EE + 255) / 256, 256, 0, stream>>>(edg, cursor, csrsrc);

    // layer 1
    gemm_all<<<RR * (NN / BN), 128, 0, stream>>>(x, W1, al1, ar1, f, el, er);
    pull_semw<<<RR * NN, 128, 0, stream>>>(starts, csrsrc, el, er, f, b1, 1,
                                           aw1, ab1, aw2, z, wv);
    reduce_beta<<<1, 256, 0, stream>>>(wv, S);
    combine_f32<<<(NN * FD + 255) / 256, 256, 0, stream>>>(z, S, out);  // hmid

    // layer 2
    gemm_all<<<RR * (NN / BN), 128, 0, stream>>>(out, W2, al2, ar2, f, el, er);
    pull_semw<<<RR * NN, 128, 0, stream>>>(starts, csrsrc, el, er, f, b2, 0,
                                           bw1, bb1, bw2, z, wv);
    reduce_beta<<<1, 256, 0, stream>>>(wv, S);
    combine_f32<<<(NN * FD + 255) / 256, 256, 0, stream>>>(z, S, out);
    return;
  }

  // ---------------- fallback: R10 CSR path (46 MB, proven) ----------------
  float* S      = (float*)d_ws;
  float* wv     = S + 16;
  float* el     = wv + (size_t)RR * NN;
  float* er     = el + (size_t)NN * 2;
  float* f      = er + (size_t)NN * 2;
  float* z      = f + (size_t)NN * FD;
  int*   cnt    = (int*)(z + (size_t)RR * NN * FD);
  int*   starts = cnt + RR * NN;
  int*   cursor = starts + RR * NP1;
  int*   csrsrc = cursor + RR * NP1;

  hipMemsetAsync(cnt, 0, (size_t)RR * NN * sizeof(int), stream);
  csr_count<<<(RR * EE + 255) / 256, 256, 0, stream>>>(edg, cnt);
  csr_scan<<<RR, 256, 0, stream>>>(cnt, starts, cursor);
  csr_scatter<<<(RR * EE + 255) / 256, 256, 0, stream>>>(edg, cursor, csrsrc);

  for (int r = 0; r < RR; ++r) {
    gemm_el_er<<<NN / 8, 128, 0, stream>>>(
        x, W1 + (size_t)r * FD * FD, al1 + r * FD, ar1 + r * FD, f, el, er);
    pull_aggr<<<NN, 128, 0, stream>>>(starts + r * NP1, csrsrc + (size_t)r * EE,
                                      el, er, f, b1 + r * FD, 1,
                                      z + (size_t)r * NN * FD);
  }
  semw_nodes<<<NN * RR / 2, 256, 0, stream>>>(z, aw1, ab1, aw2, wv);
  reduce_beta<<<1, 256, 0, stream>>>(wv, S);
  combine_f32<<<(NN * FD + 255) / 256, 256, 0, stream>>>(z, S, out);

  for (int r = 0; r < RR; ++r) {
    gemm_el_er<<<NN / 8, 128, 0, stream>>>(
        out, W2 + (size_t)r * FD * FD, al2 + r * FD, ar2 + r * FD, f, el, er);
    pull_aggr<<<NN, 128, 0, stream>>>(starts + r * NP1, csrsrc + (size_t)r * EE,
                                      el, er, f, b2 + r * FD, 0,
                                      z + (size_t)r * NN * FD);
  }
  semw_nodes<<<NN * RR / 2, 256, 0, stream>>>(z, bw1, bb1, bw2, wv);
  reduce_beta<<<1, 256, 0, stream>>>(wv, S);
  combine_f32<<<(NN * FD + 255) / 256, 256, 0, stream>>>(z, S, out);
}

// Round 14
// 640.293 us; speedup vs baseline: 1.1651x; 1.1651x over previous
//
#include <hip/hip_runtime.h>
#include <hip/hip_bf16.h>

// Established facts (R3-R13): d_in = setup_inputs() dict order; floats fp32;
// edges int32; output fp32 [20000,128]. R12=658us (LDS gemm), R13=746us
// (scalar-load gemm REGRESSED: s_load chain serializes, VALUBusy 14%).
// This round: gemm v4 = LDS-staged, 64-thread wave, 2 columns/thread ->
// ds:VALU ratio 6144:8192 cyc (VALU-bound). pull_semw keeps x8 unroll.
#define NN 20000
#define RR 3
#define EE 320000
#define FD 128
#define AH 32
#define NP1 (NN + 1)
#define NEG_SLOPE 0.2f

__device__ __forceinline__ int clamp_idx(int v) {
  v = v < 0 ? 0 : v;
  return v < NN ? v : NN - 1;
}
__device__ __forceinline__ float leaky_exp(float e) {
  e = e > 0.f ? e : NEG_SLOPE * e;
  return __expf(e);
}

// ----------------------------- CSR build -----------------------------------
__global__ void csr_count(const int* __restrict__ edg, int* __restrict__ cnt) {
  const int idx = blockIdx.x * blockDim.x + threadIdx.x;
  if (idx >= RR * EE) return;
  const int r = idx / EE, k = idx - r * EE;
  const int dst = clamp_idx(edg[(size_t)r * 2 * EE + EE + k]);
  atomicAdd(&cnt[r * NN + dst], 1);
}

__global__ void csr_scan(const int* __restrict__ cnt, int* __restrict__ starts,
                         int* __restrict__ cursor) {
  __shared__ int part[256];
  const int r = blockIdx.x, t = threadIdx.x;
  const int CH = (NN + 255) / 256;  // 79
  const int lo = t * CH, hi = min(lo + CH, NN);
  int s = 0;
  for (int i = lo; i < hi; ++i) s += cnt[r * NN + i];
  part[t] = s;
  __syncthreads();
  if (t == 0) {
    int run = 0;
    for (int i = 0; i < 256; ++i) { const int v = part[i]; part[i] = run; run += v; }
  }
  __syncthreads();
  int run = part[t];
  for (int i = lo; i < hi; ++i) {
    starts[r * NP1 + i] = run;
    cursor[r * NP1 + i] = run;
    run += cnt[r * NN + i];
  }
  if (t == 255) starts[r * NP1 + NN] = run;
}

__global__ void csr_scatter(const int* __restrict__ edg, int* __restrict__ cursor,
                            int* __restrict__ csrsrc) {
  const int idx = blockIdx.x * blockDim.x + threadIdx.x;
  if (idx >= RR * EE) return;
  const int r = idx / EE, k = idx - r * EE;
  const int src = clamp_idx(edg[(size_t)r * 2 * EE + k]);
  const int dst = clamp_idx(edg[(size_t)r * 2 * EE + EE + k]);
  const int pos = atomicAdd(&cursor[r * NP1 + dst], 1);
  csrsrc[(size_t)r * EE + pos] = src;
}

// ---------------------------------------------------------------------------
// Merged gemm v4: f[r] = h_in @ W[r], el/er fused.
// Block = 64 threads (1 wave), BN=16 nodes; thread j owns columns j (head 0)
// and j+64 (head 1). Each ds_read_b128 of the h-tile feeds 8 FMAs ->
// ds 512x12=6144 cyc < VALU 4096x2=8192 cyc per wave: VALU-bound.
// ---------------------------------------------------------------------------
#define BN 16
__global__ void __launch_bounds__(64, 4) gemm_all(
    const float* __restrict__ hin,  // [N,128]
    const float* __restrict__ W,    // [3,128,128]
    const float* __restrict__ al,   // [3,128]
    const float* __restrict__ ar,   // [3,128]
    float* __restrict__ f,          // [3,N,128]
    float* __restrict__ el,         // [3,N,2]
    float* __restrict__ er) {
  __shared__ float lh[BN * FD];  // 8 KB
  const int blocksPerRel = NN / BN;  // 1250
  const int r = blockIdx.x / blocksPerRel;
  const int n0 = (blockIdx.x % blocksPerRel) * BN;
  const int j = threadIdx.x;  // 0..63

  // Stage h tile: 2048 floats = 512 float4, 8 per thread.
  {
    const float4* s4 = (const float4*)&hin[(size_t)n0 * FD];
    float4* d4 = (float4*)lh;
#pragma unroll
    for (int t = 0; t < 8; ++t) d4[j + 64 * t] = s4[j + 64 * t];
  }
  __syncthreads();

  const float* Wr = W + (size_t)r * FD * FD;
  float acc0[BN], acc1[BN];
#pragma unroll
  for (int i = 0; i < BN; ++i) { acc0[i] = 0.f; acc1[i] = 0.f; }

  for (int k4 = 0; k4 < FD; k4 += 4) {
    const float wa0 = Wr[(size_t)(k4 + 0) * FD + j];
    const float wb0 = Wr[(size_t)(k4 + 0) * FD + j + 64];
    const float wa1 = Wr[(size_t)(k4 + 1) * FD + j];
    const float wb1 = Wr[(size_t)(k4 + 1) * FD + j + 64];
    const float wa2 = Wr[(size_t)(k4 + 2) * FD + j];
    const float wb2 = Wr[(size_t)(k4 + 2) * FD + j + 64];
    const float wa3 = Wr[(size_t)(k4 + 3) * FD + j];
    const float wb3 = Wr[(size_t)(k4 + 3) * FD + j + 64];
#pragma unroll
    for (int i = 0; i < BN; ++i) {
      const float4 h4 = *(const float4*)&lh[i * FD + k4];  // 1 b128 -> 8 FMA
      acc0[i] = fmaf(h4.x, wa0, fmaf(h4.y, wa1, fmaf(h4.z, wa2, fmaf(h4.w, wa3, acc0[i]))));
      acc1[i] = fmaf(h4.x, wb0, fmaf(h4.y, wb1, fmaf(h4.z, wb2, fmaf(h4.w, wb3, acc1[i]))));
    }
  }

  const float al0 = al[r * FD + j];
  const float al1v = al[r * FD + j + 64];
  const float ar0 = ar[r * FD + j];
  const float ar1v = ar[r * FD + j + 64];

#pragma unroll
  for (int i = 0; i < BN; ++i) {
    const size_t row = ((size_t)r * NN + n0 + i) * FD;
    f[row + j] = acc0[i];
    f[row + j + 64] = acc1[i];
    // head 0 from acc0 (cols 0..63), head 1 from acc1 (cols 64..127);
    // same 64-value sets + same butterfly order as R12/R13 -> bitwise equal.
    float e0 = acc0[i] * al0;
    float e1 = acc1[i] * al1v;
    float u0 = acc0[i] * ar0;
    float u1 = acc1[i] * ar1v;
#pragma unroll
    for (int off = 32; off > 0; off >>= 1) {
      e0 += __shfl_down(e0, off, 64);
      e1 += __shfl_down(e1, off, 64);
      u0 += __shfl_down(u0, off, 64);
      u1 += __shfl_down(u1, off, 64);
    }
    if (j == 0) {
      const size_t base = ((size_t)r * NN + n0 + i) * 2;
      el[base + 0] = e0;
      el[base + 1] = e1;
      er[base + 0] = u0;
      er[base + 1] = u1;
    }
  }
}

// ---------------------------------------------------------------------------
// Fused pull + semantic-attention logit (R13, x8 unroll, order-preserving).
// ---------------------------------------------------------------------------
__global__ void pull_semw(const int* __restrict__ starts,  // [3,NP1]
                          const int* __restrict__ csrsrc,  // [3,E]
                          const float* __restrict__ el,    // [3,N,2]
                          const float* __restrict__ er,
                          const float* __restrict__ f,     // [3,N,128]
                          const float* __restrict__ b,     // [3,128]
                          int do_relu,
                          const float* __restrict__ aw1,   // [128,32]
                          const float* __restrict__ ab1,   // [32]
                          const float* __restrict__ aw2,   // [32]
                          float* __restrict__ z,           // [3,N,128]
                          float* __restrict__ wv) {        // [3,N]
  __shared__ float lz[FD];
  __shared__ float red[4][AH];
  __shared__ float wcol[AH];
  const int rn = blockIdx.x;
  const int r = rn / NN;
  const int n = rn - r * NN;
  const int j = threadIdx.x;
  const int h = j >> 6;
  const int* st = starts + r * NP1;
  const int* cs = csrsrc + (size_t)r * EE;
  const float* elr = el + (size_t)r * NN * 2;
  const float* fr = f + (size_t)r * NN * FD;
  const int s0 = st[n], s1 = st[n + 1];
  const float ern = er[((size_t)r * NN + n) * 2 + h];

  float acc = 0.f, den = 0.f;
  int p = s0;
  for (; p + 8 <= s1; p += 8) {
    const int i0 = cs[p + 0];
    const int i1 = cs[p + 1];
    const int i2 = cs[p + 2];
    const int i3 = cs[p + 3];
    const int i4 = cs[p + 4];
    const int i5 = cs[p + 5];
    const int i6 = cs[p + 6];
    const int i7 = cs[p + 7];
    const float w0 = leaky_exp(elr[(size_t)i0 * 2 + h] + ern);
    const float w1 = leaky_exp(elr[(size_t)i1 * 2 + h] + ern);
    const float w2 = leaky_exp(elr[(size_t)i2 * 2 + h] + ern);
    const float w3 = leaky_exp(elr[(size_t)i3 * 2 + h] + ern);
    const float w4 = leaky_exp(elr[(size_t)i4 * 2 + h] + ern);
    const float w5 = leaky_exp(elr[(size_t)i5 * 2 + h] + ern);
    const float w6 = leaky_exp(elr[(size_t)i6 * 2 + h] + ern);
    const float w7 = leaky_exp(elr[(size_t)i7 * 2 + h] + ern);
    const float f0 = fr[(size_t)i0 * FD + j];
    const float f1 = fr[(size_t)i1 * FD + j];
    const float f2 = fr[(size_t)i2 * FD + j];
    const float f3 = fr[(size_t)i3 * FD + j];
    const float f4 = fr[(size_t)i4 * FD + j];
    const float f5 = fr[(size_t)i5 * FD + j];
    const float f6 = fr[(size_t)i6 * FD + j];
    const float f7 = fr[(size_t)i7 * FD + j];
    den += w0; acc += w0 * f0;
    den += w1; acc += w1 * f1;
    den += w2; acc += w2 * f2;
    den += w3; acc += w3 * f3;
    den += w4; acc += w4 * f4;
    den += w5; acc += w5 * f5;
    den += w6; acc += w6 * f6;
    den += w7; acc += w7 * f7;
  }
  for (; p + 4 <= s1; p += 4) {
    const int i0 = cs[p + 0];
    const int i1 = cs[p + 1];
    const int i2 = cs[p + 2];
    const int i3 = cs[p + 3];
    const float w0 = leaky_exp(elr[(size_t)i0 * 2 + h] + ern);
    const float w1 = leaky_exp(elr[(size_t)i1 * 2 + h] + ern);
    const float w2 = leaky_exp(elr[(size_t)i2 * 2 + h] + ern);
    const float w3 = leaky_exp(elr[(size_t)i3 * 2 + h] + ern);
    const float f0 = fr[(size_t)i0 * FD + j];
    const float f1 = fr[(size_t)i1 * FD + j];
    const float f2 = fr[(size_t)i2 * FD + j];
    const float f3 = fr[(size_t)i3 * FD + j];
    den += w0; acc += w0 * f0;
    den += w1; acc += w1 * f1;
    den += w2; acc += w2 * f2;
    den += w3; acc += w3 * f3;
  }
  for (; p < s1; ++p) {
    const int src = cs[p];
    const float w = leaky_exp(elr[(size_t)src * 2 + h] + ern);
    den += w;
    acc += w * fr[(size_t)src * FD + j];
  }

  float v = acc / fmaxf(den, 1e-9f) + b[r * FD + j];
  if (do_relu) v = fmaxf(v, 0.f);
  z[(size_t)rn * FD + j] = v;

  lz[j] = v;
  __syncthreads();
  const int col = j & 31;
  const int part = j >> 5;
  float a2 = 0.f;
#pragma unroll
  for (int kk = 0; kk < 32; ++kk) {
    const int k = part * 32 + kk;
    a2 += lz[k] * aw1[(size_t)k * AH + col];
  }
  red[part][col] = a2;
  __syncthreads();
  if (part == 0)
    wcol[col] = tanhf(red[0][col] + red[1][col] + red[2][col] + red[3][col] +
                      ab1[col]) * aw2[col];
  __syncthreads();
  if (j == 0) {
    float w = 0.f;
#pragma unroll
    for (int c = 0; c < AH; ++c) w += wcol[c];
    wv[rn] = w;
  }
}

// Fused reduce + beta
__global__ void reduce_beta(const float* __restrict__ wv, float* __restrict__ S) {
  __shared__ float p[256];
  const int t = threadIdx.x;
  float tot[RR];
  for (int r = 0; r < RR; ++r) {
    float s = 0.f;
    for (int n = t; n < NN; n += 256) s += wv[(size_t)r * NN + n];
    p[t] = s;
    __syncthreads();
    for (int off = 128; off > 0; off >>= 1) {
      if (t < off) p[t] += p[t + off];
      __syncthreads();
    }
    tot[r] = p[0];
    __syncthreads();
  }
  if (t == 0) {
    S[0] = tot[0]; S[1] = tot[1]; S[2] = tot[2];
    float w0 = tot[0] / (float)NN, w1 = tot[1] / (float)NN, w2 = tot[2] / (float)NN;
    float mx = fmaxf(w0, fmaxf(w1, w2));
    float e0 = __expf(w0 - mx), e1 = __expf(w1 - mx), e2 = __expf(w2 - mx);
    float inv = 1.f / (e0 + e1 + e2);
    S[4] = e0 * inv; S[5] = e1 * inv; S[6] = e2 * inv;
  }
}

__global__ void combine_f32(const float* __restrict__ z,
                            const float* __restrict__ S,
                            float* __restrict__ out) {
  const int idx = blockIdx.x * blockDim.x + threadIdx.x;
  if (idx >= NN * FD) return;
  out[idx] = S[4] * z[idx] + S[5] * z[(size_t)NN * FD + idx] +
             S[6] * z[2 * (size_t)NN * FD + idx];
}

// ------------------- fallback kernels (R10 CSR path, proven) ----------------
__global__ void gemm_el_er(const float* __restrict__ hin,
                           const float* __restrict__ W,
                           const float* __restrict__ al,
                           const float* __restrict__ ar,
                           float* __restrict__ f,
                           float* __restrict__ el,
                           float* __restrict__ er) {
  const int B8 = 8;
  __shared__ float lh[B8 * FD];
  const int j = threadIdx.x;
  const int n0 = blockIdx.x * B8;
#pragma unroll
  for (int i = 0; i < B8; ++i)
    lh[i * FD + j] = hin[(size_t)(n0 + i) * FD + j];
  __syncthreads();
  float acc[B8];
#pragma unroll
  for (int i = 0; i < B8; ++i) acc[i] = 0.f;
  for (int k = 0; k < FD; ++k) {
    const float w = W[(size_t)k * FD + j];
#pragma unroll
    for (int i = 0; i < B8; ++i) acc[i] += lh[i * FD + k] * w;
  }
  const float alv = al[j];
  const float arv = ar[j];
#pragma unroll
  for (int i = 0; i < B8; ++i) f[(size_t)(n0 + i) * FD + j] = acc[i];
  __syncthreads();
#pragma unroll
  for (int i = 0; i < B8; ++i) lh[i * FD + j] = acc[i] * alv;
  __syncthreads();
  if (j < B8 * 2) {
    const int i = j >> 1, h = j & 1;
    const float* p = &lh[i * FD + h * 64];
    float s = 0.f;
    for (int d = 0; d < 64; ++d) s += p[d];
    el[(size_t)(n0 + i) * 2 + h] = s;
  }
  __syncthreads();
#pragma unroll
  for (int i = 0; i < B8; ++i) lh[i * FD + j] = acc[i] * arv;
  __syncthreads();
  if (j < B8 * 2) {
    const int i = j >> 1, h = j & 1;
    const float* p = &lh[i * FD + h * 64];
    float s = 0.f;
    for (int d = 0; d < 64; ++d) s += p[d];
    er[(size_t)(n0 + i) * 2 + h] = s;
  }
}

__global__ void pull_aggr(const int* __restrict__ starts,
                          const int* __restrict__ csrsrc,
                          const float* __restrict__ el,
                          const float* __restrict__ er,
                          const float* __restrict__ f,
                          const float* __restrict__ b,
                          int do_relu,
                          float* __restrict__ z) {
  const int n = blockIdx.x;
  const int j = threadIdx.x;
  const int h = j >> 6;
  const int s0 = starts[n], s1 = starts[n + 1];
  const float ern = er[(size_t)n * 2 + h];
  float acc = 0.f, den = 0.f;
  for (int p = s0; p < s1; ++p) {
    const int src = csrsrc[p];
    const float w = leaky_exp(el[(size_t)src * 2 + h] + ern);
    den += w;
    acc += w * f[(size_t)src * FD + j];
  }
  float v = acc / fmaxf(den, 1e-9f) + b[j];
  if (do_relu) v = fmaxf(v, 0.f);
  z[(size_t)n * FD + j] = v;
}

__global__ void semw_nodes(const float* __restrict__ z,
                           const float* __restrict__ aw1,
                           const float* __restrict__ ab1,
                           const float* __restrict__ aw2,
                           float* __restrict__ wv) {
  __shared__ float lz[2][FD];
  __shared__ float red[2][4][AH];
  __shared__ float wcol[2][AH];
  const int g = threadIdx.x >> 7;
  const int t = threadIdx.x & 127;
  const int pair = blockIdx.x * 2 + g;
  const int n = pair / RR;
  const int r = pair - n * RR;
  lz[g][t] = z[((size_t)r * NN + n) * FD + t];
  __syncthreads();
  const int col = t & 31;
  const int part = t >> 5;
  float acc = 0.f;
#pragma unroll
  for (int kk = 0; kk < 32; ++kk) {
    const int k = part * 32 + kk;
    acc += lz[g][k] * aw1[(size_t)k * AH + col];
  }
  red[g][part][col] = acc;
  __syncthreads();
  if (part == 0) {
    float s = red[g][0][col] + red[g][1][col] + red[g][2][col] + red[g][3][col];
    wcol[g][col] = tanhf(s + ab1[col]) * aw2[col];
  }
  __syncthreads();
  if (t == 0) {
    float w = 0.f;
#pragma unroll
    for (int c = 0; c < AH; ++c) w += wcol[g][c];
    wv[(size_t)r * NN + n] = w;
  }
}

// ---------------------------------------------------------------------------
extern "C" void kernel_launch(void* const* d_in, const int* in_sizes, int n_in,
                              void* d_out, int out_size, void* d_ws, size_t ws_size,
                              hipStream_t stream) {
  const float* x   = (const float*)d_in[0];
  const int*   edg = (const int*)d_in[1];
  const float* W1  = (const float*)d_in[2];
  const float* al1 = (const float*)d_in[3];
  const float* ar1 = (const float*)d_in[4];
  const float* b1  = (const float*)d_in[5];
  const float* W2  = (const float*)d_in[6];
  const float* al2 = (const float*)d_in[7];
  const float* ar2 = (const float*)d_in[8];
  const float* b2  = (const float*)d_in[9];
  const float* aw1 = (const float*)d_in[10];
  const float* ab1 = (const float*)d_in[11];
  const float* aw2 = (const float*)d_in[12];
  const float* bw1 = (const float*)d_in[13];
  const float* bb1 = (const float*)d_in[14];
  const float* bw2 = (const float*)d_in[15];
  float* out = (float*)d_out;

  const size_t need_big = 67200128;  // merged path: 67.2 MB (proven to fit)
  if (ws_size >= need_big) {
    float* S      = (float*)d_ws;                    // 16
    float* wv     = S + 16;                          // RR*NN
    float* el     = wv + (size_t)RR * NN;            // RR*NN*2
    float* er     = el + (size_t)RR * NN * 2;        // RR*NN*2
    float* f      = er + (size_t)RR * NN * 2;        // RR*NN*FD
    float* z      = f + (size_t)RR * NN * FD;        // RR*NN*FD
    int*   cnt    = (int*)(z + (size_t)RR * NN * FD);// RR*NN
    int*   starts = cnt + RR * NN;                   // RR*NP1
    int*   cursor = starts + RR * NP1;               // RR*NP1
    int*   csrsrc = cursor + RR * NP1;               // RR*EE

    hipMemsetAsync(cnt, 0, (size_t)RR * NN * sizeof(int), stream);
    csr_count<<<(RR * EE + 255) / 256, 256, 0, stream>>>(edg, cnt);
    csr_scan<<<RR, 256, 0, stream>>>(cnt, starts, cursor);
    csr_scatter<<<(RR * EE + 255) / 256, 256, 0, stream>>>(edg, cursor, csrsrc);

    // layer 1
    gemm_all<<<RR * (NN / BN), 64, 0, stream>>>(x, W1, al1, ar1, f, el, er);
    pull_semw<<<RR * NN, 128, 0, stream>>>(starts, csrsrc, el, er, f, b1, 1,
                                           aw1, ab1, aw2, z, wv);
    reduce_beta<<<1, 256, 0, stream>>>(wv, S);
    combine_f32<<<(NN * FD + 255) / 256, 256, 0, stream>>>(z, S, out);  // hmid

    // layer 2
    gemm_all<<<RR * (NN / BN), 64, 0, stream>>>(out, W2, al2, ar2, f, el, er);
    pull_semw<<<RR * NN, 128, 0, stream>>>(starts, csrsrc, el, er, f, b2, 0,
                                           bw1, bb1, bw2, z, wv);
    reduce_beta<<<1, 256, 0, stream>>>(wv, S);
    combine_f32<<<(NN * FD + 255) / 256, 256, 0, stream>>>(z, S, out);
    return;
  }

  // ---------------- fallback: R10 CSR path (46 MB, proven) ----------------
  float* S      = (float*)d_ws;
  float* wv     = S + 16;
  float* el     = wv + (size_t)RR * NN;
  float* er     = el + (size_t)NN * 2;
  float* f      = er + (size_t)NN * 2;
  float* z      = f + (size_t)NN * FD;
  int*   cnt    = (int*)(z + (size_t)RR * NN * FD);
  int*   starts = cnt + RR * NN;
  int*   cursor = starts + RR * NP1;
  int*   csrsrc = cursor + RR * NP1;

  hipMemsetAsync(cnt, 0, (size_t)RR * NN * sizeof(int), stream);
  csr_count<<<(RR * EE + 255) / 256, 256, 0, stream>>>(edg, cnt);
  csr_scan<<<RR, 256, 0, stream>>>(cnt, starts, cursor);
  csr_scatter<<<(RR * EE + 255) / 256, 256, 0, stream>>>(edg, cursor, csrsrc);

  for (int r = 0; r < RR; ++r) {
    gemm_el_er<<<NN / 8, 128, 0, stream>>>(
        x, W1 + (size_t)r * FD * FD, al1 + r * FD, ar1 + r * FD, f, el, er);
    pull_aggr<<<NN, 128, 0, stream>>>(starts + r * NP1, csrsrc + (size_t)r * EE,
                                      el, er, f, b1 + r * FD, 1,
                                      z + (size_t)r * NN * FD);
  }
  semw_nodes<<<NN * RR / 2, 256, 0, stream>>>(z, aw1, ab1, aw2, wv);
  reduce_beta<<<1, 256, 0, stream>>>(wv, S);
  combine_f32<<<(NN * FD + 255) / 256, 256, 0, stream>>>(z, S, out);

  for (int r = 0; r < RR; ++r) {
    gemm_el_er<<<NN / 8, 128, 0, stream>>>(
        out, W2 + (size_t)r * FD * FD, al2 + r * FD, ar2 + r * FD, f, el, er);
    pull_aggr<<<NN, 128, 0, stream>>>(starts + r * NP1, csrsrc + (size_t)r * EE,
                                      el, er, f, b2 + r * FD, 0,
                                      z + (size_t)r * NN * FD);
  }
  semw_nodes<<<NN * RR / 2, 256, 0, stream>>>(z, bw1, bb1, bw2, wv);
  reduce_beta<<<1, 256, 0, stream>>>(wv, S);
  combine_f32<<<(NN * FD + 255) / 256, 256, 0, stream>>>(z, S, out);
}

// Round 16
// 615.666 us; speedup vs baseline: 1.2117x; 1.0400x over previous
//
#include <hip/hip_runtime.h>
#include <hip/hip_bf16.h>

// Established facts (R3-R14): d_in = setup_inputs() dict order; floats fp32;
// edges int32; output fp32 [20000,128]. R14=640us, pull_semw VALU-bound
// (80% VALUBusy, 2 waves/block duplicate per-edge work) with 209MB gather.
// This round (R15 fixed): pull = 1 wave/block + float2 cols (halves per-edge
// VALU) and f staged as bf16 via manual RNE (the __hip_bfloat16.data member
// doesn't exist on this ROCm -> hand-rolled bit conversion).
#define NN 20000
#define RR 3
#define EE 320000
#define FD 128
#define AH 32
#define NP1 (NN + 1)
#define NEG_SLOPE 0.2f

__device__ __forceinline__ int clamp_idx(int v) {
  v = v < 0 ? 0 : v;
  return v < NN ? v : NN - 1;
}
__device__ __forceinline__ float leaky_exp(float e) {
  e = e > 0.f ? e : NEG_SLOPE * e;
  return __expf(e);
}
__device__ __forceinline__ float bf2f(unsigned short u) {
  union { unsigned int i; float f; } c;
  c.i = ((unsigned int)u) << 16;
  return c.f;
}
// fp32 -> bf16 with round-to-nearest-even (values are finite, |v| ~ O(1))
__device__ __forceinline__ unsigned short f2bf(float v) {
  union { float f; unsigned int i; } c;
  c.f = v;
  const unsigned int u = c.i;
  return (unsigned short)((u + 0x7fffu + ((u >> 16) & 1u)) >> 16);
}

// ----------------------------- CSR build -----------------------------------
__global__ void csr_count(const int* __restrict__ edg, int* __restrict__ cnt) {
  const int idx = blockIdx.x * blockDim.x + threadIdx.x;
  if (idx >= RR * EE) return;
  const int r = idx / EE, k = idx - r * EE;
  const int dst = clamp_idx(edg[(size_t)r * 2 * EE + EE + k]);
  atomicAdd(&cnt[r * NN + dst], 1);
}

__global__ void csr_scan(const int* __restrict__ cnt, int* __restrict__ starts,
                         int* __restrict__ cursor) {
  __shared__ int part[256];
  const int r = blockIdx.x, t = threadIdx.x;
  const int CH = (NN + 255) / 256;  // 79
  const int lo = t * CH, hi = min(lo + CH, NN);
  int s = 0;
  for (int i = lo; i < hi; ++i) s += cnt[r * NN + i];
  part[t] = s;
  __syncthreads();
  if (t == 0) {
    int run = 0;
    for (int i = 0; i < 256; ++i) { const int v = part[i]; part[i] = run; run += v; }
  }
  __syncthreads();
  int run = part[t];
  for (int i = lo; i < hi; ++i) {
    starts[r * NP1 + i] = run;
    cursor[r * NP1 + i] = run;
    run += cnt[r * NN + i];
  }
  if (t == 255) starts[r * NP1 + NN] = run;
}

__global__ void csr_scatter(const int* __restrict__ edg, int* __restrict__ cursor,
                            int* __restrict__ csrsrc) {
  const int idx = blockIdx.x * blockDim.x + threadIdx.x;
  if (idx >= RR * EE) return;
  const int r = idx / EE, k = idx - r * EE;
  const int src = clamp_idx(edg[(size_t)r * 2 * EE + k]);
  const int dst = clamp_idx(edg[(size_t)r * 2 * EE + EE + k]);
  const int pos = atomicAdd(&cursor[r * NP1 + dst], 1);
  csrsrc[(size_t)r * EE + pos] = src;
}

// ---------------------------------------------------------------------------
// Merged gemm (R14 v4 + bf16 f store): block = 1 wave, BN=16 nodes,
// thread j owns cols j (head 0) and j+64 (head 1). el/er via shfl.
// ---------------------------------------------------------------------------
#define BN 16
__global__ void __launch_bounds__(64, 4) gemm_all(
    const float* __restrict__ hin,            // [N,128]
    const float* __restrict__ W,              // [3,128,128]
    const float* __restrict__ al,             // [3,128]
    const float* __restrict__ ar,             // [3,128]
    unsigned short* __restrict__ fb,          // [3,N,128] bf16
    float* __restrict__ el,                   // [3,N,2]
    float* __restrict__ er) {
  __shared__ float lh[BN * FD];  // 8 KB
  const int blocksPerRel = NN / BN;  // 1250
  const int r = blockIdx.x / blocksPerRel;
  const int n0 = (blockIdx.x % blocksPerRel) * BN;
  const int j = threadIdx.x;  // 0..63

  {
    const float4* s4 = (const float4*)&hin[(size_t)n0 * FD];
    float4* d4 = (float4*)lh;
#pragma unroll
    for (int t = 0; t < 8; ++t) d4[j + 64 * t] = s4[j + 64 * t];
  }
  __syncthreads();

  const float* Wr = W + (size_t)r * FD * FD;
  float acc0[BN], acc1[BN];
#pragma unroll
  for (int i = 0; i < BN; ++i) { acc0[i] = 0.f; acc1[i] = 0.f; }

  for (int k4 = 0; k4 < FD; k4 += 4) {
    const float wa0 = Wr[(size_t)(k4 + 0) * FD + j];
    const float wb0 = Wr[(size_t)(k4 + 0) * FD + j + 64];
    const float wa1 = Wr[(size_t)(k4 + 1) * FD + j];
    const float wb1 = Wr[(size_t)(k4 + 1) * FD + j + 64];
    const float wa2 = Wr[(size_t)(k4 + 2) * FD + j];
    const float wb2 = Wr[(size_t)(k4 + 2) * FD + j + 64];
    const float wa3 = Wr[(size_t)(k4 + 3) * FD + j];
    const float wb3 = Wr[(size_t)(k4 + 3) * FD + j + 64];
#pragma unroll
    for (int i = 0; i < BN; ++i) {
      const float4 h4 = *(const float4*)&lh[i * FD + k4];
      acc0[i] = fmaf(h4.x, wa0, fmaf(h4.y, wa1, fmaf(h4.z, wa2, fmaf(h4.w, wa3, acc0[i]))));
      acc1[i] = fmaf(h4.x, wb0, fmaf(h4.y, wb1, fmaf(h4.z, wb2, fmaf(h4.w, wb3, acc1[i]))));
    }
  }

  const float al0 = al[r * FD + j];
  const float al1v = al[r * FD + j + 64];
  const float ar0 = ar[r * FD + j];
  const float ar1v = ar[r * FD + j + 64];

#pragma unroll
  for (int i = 0; i < BN; ++i) {
    const size_t row = ((size_t)r * NN + n0 + i) * FD;
    fb[row + j] = f2bf(acc0[i]);
    fb[row + j + 64] = f2bf(acc1[i]);
    float e0 = acc0[i] * al0;
    float e1 = acc1[i] * al1v;
    float u0 = acc0[i] * ar0;
    float u1 = acc1[i] * ar1v;
#pragma unroll
    for (int off = 32; off > 0; off >>= 1) {
      e0 += __shfl_down(e0, off, 64);
      e1 += __shfl_down(e1, off, 64);
      u0 += __shfl_down(u0, off, 64);
      u1 += __shfl_down(u1, off, 64);
    }
    if (j == 0) {
      const size_t base = ((size_t)r * NN + n0 + i) * 2;
      el[base + 0] = e0;
      el[base + 1] = e1;
      er[base + 0] = u0;
      er[base + 1] = u1;
    }
  }
}

// ---------------------------------------------------------------------------
// Fused pull + semantic logit. Block = 1 wave (64 threads); thread j owns
// columns 2j, 2j+1 (same head h=j>>5). f gathered as bf16x2 (4 B/lane).
// Per-column accumulation order unchanged; x8/x4/x1 unroll for MLP.
// ---------------------------------------------------------------------------
__global__ void __launch_bounds__(64, 4) pull_semw(
    const int* __restrict__ starts,   // [3,NP1]
    const int* __restrict__ csrsrc,   // [3,E]
    const float* __restrict__ el,     // [3,N,2]
    const float* __restrict__ er,
    const unsigned short* __restrict__ fb,  // [3,N,128] bf16
    const float* __restrict__ b,      // [3,128]
    int do_relu,
    const float* __restrict__ aw1,    // [128,32]
    const float* __restrict__ ab1,    // [32]
    const float* __restrict__ aw2,    // [32]
    float* __restrict__ z,            // [3,N,128]
    float* __restrict__ wv) {         // [3,N]
  __shared__ float lz[FD];
  __shared__ float red[4][AH];
  __shared__ float wcol[AH];
  const int rn = blockIdx.x;
  const int r = rn / NN;
  const int n = rn - r * NN;
  const int j = threadIdx.x;       // 0..63
  const int c = j * 2;             // columns c, c+1
  const int h = j >> 5;            // head
  const int* st = starts + r * NP1;
  const int* cs = csrsrc + (size_t)r * EE;
  const float* elr = el + (size_t)r * NN * 2;
  const unsigned short* fr = fb + (size_t)r * NN * FD;
  const int s0 = st[n], s1 = st[n + 1];
  const float ern = er[((size_t)r * NN + n) * 2 + h];

  float ax = 0.f, ay = 0.f, den = 0.f;
  int p = s0;
#define EDGE(iK)                                                        \
  {                                                                     \
    const int sK = cs[p + iK];                                          \
    const float wK = leaky_exp(elr[(size_t)sK * 2 + h] + ern);          \
    const unsigned int fvK = *(const unsigned int*)&fr[(size_t)sK * FD + c]; \
    den += wK;                                                          \
    ax += wK * bf2f((unsigned short)(fvK & 0xffff));                    \
    ay += wK * bf2f((unsigned short)(fvK >> 16));                       \
  }
  for (; p + 8 <= s1; p += 8) {
    EDGE(0) EDGE(1) EDGE(2) EDGE(3) EDGE(4) EDGE(5) EDGE(6) EDGE(7)
  }
  for (; p + 4 <= s1; p += 4) {
    EDGE(0) EDGE(1) EDGE(2) EDGE(3)
  }
  for (; p < s1; ++p) {
    EDGE(0)
  }
#undef EDGE

  const float inv = 1.f / fmaxf(den, 1e-9f);
  float vx = ax * inv + b[r * FD + c];
  float vy = ay * inv + b[r * FD + c + 1];
  if (do_relu) { vx = fmaxf(vx, 0.f); vy = fmaxf(vy, 0.f); }
  float2* zrow = (float2*)&z[(size_t)rn * FD];
  zrow[j] = make_float2(vx, vy);

  // ---- fused semantic-attention logit ----
  lz[c] = vx;
  lz[c + 1] = vy;
  __syncthreads();
  const int col = j & 31;
  const int p0 = j >> 5;  // 0..1; also handle p0+2
#pragma unroll
  for (int t = 0; t < 2; ++t) {
    const int part = p0 + 2 * t;
    float a2 = 0.f;
#pragma unroll
    for (int kk = 0; kk < 32; ++kk) {
      const int k = part * 32 + kk;
      a2 += lz[k] * aw1[(size_t)k * AH + col];
    }
    red[part][col] = a2;
  }
  __syncthreads();
  if (j < 32)
    wcol[j] = tanhf(red[0][j] + red[1][j] + red[2][j] + red[3][j] + ab1[j]) *
              aw2[j];
  __syncthreads();
  if (j == 0) {
    float w = 0.f;
#pragma unroll
    for (int cix = 0; cix < AH; ++cix) w += wcol[cix];
    wv[rn] = w;
  }
}

// Fused reduce + beta
__global__ void reduce_beta(const float* __restrict__ wv, float* __restrict__ S) {
  __shared__ float p[256];
  const int t = threadIdx.x;
  float tot[RR];
  for (int r = 0; r < RR; ++r) {
    float s = 0.f;
    for (int n = t; n < NN; n += 256) s += wv[(size_t)r * NN + n];
    p[t] = s;
    __syncthreads();
    for (int off = 128; off > 0; off >>= 1) {
      if (t < off) p[t] += p[t + off];
      __syncthreads();
    }
    tot[r] = p[0];
    __syncthreads();
  }
  if (t == 0) {
    S[0] = tot[0]; S[1] = tot[1]; S[2] = tot[2];
    float w0 = tot[0] / (float)NN, w1 = tot[1] / (float)NN, w2 = tot[2] / (float)NN;
    float mx = fmaxf(w0, fmaxf(w1, w2));
    float e0 = __expf(w0 - mx), e1 = __expf(w1 - mx), e2 = __expf(w2 - mx);
    float inv = 1.f / (e0 + e1 + e2);
    S[4] = e0 * inv; S[5] = e1 * inv; S[6] = e2 * inv;
  }
}

__global__ void combine_f32(const float* __restrict__ z,
                            const float* __restrict__ S,
                            float* __restrict__ out) {
  const int idx = blockIdx.x * blockDim.x + threadIdx.x;
  if (idx >= NN * FD) return;
  out[idx] = S[4] * z[idx] + S[5] * z[(size_t)NN * FD + idx] +
             S[6] * z[2 * (size_t)NN * FD + idx];
}

// ------------------- fallback kernels (R10 CSR path, proven) ----------------
__global__ void gemm_el_er(const float* __restrict__ hin,
                           const float* __restrict__ W,
                           const float* __restrict__ al,
                           const float* __restrict__ ar,
                           float* __restrict__ f,
                           float* __restrict__ el,
                           float* __restrict__ er) {
  const int B8 = 8;
  __shared__ float lh[B8 * FD];
  const int j = threadIdx.x;
  const int n0 = blockIdx.x * B8;
#pragma unroll
  for (int i = 0; i < B8; ++i)
    lh[i * FD + j] = hin[(size_t)(n0 + i) * FD + j];
  __syncthreads();
  float acc[B8];
#pragma unroll
  for (int i = 0; i < B8; ++i) acc[i] = 0.f;
  for (int k = 0; k < FD; ++k) {
    const float w = W[(size_t)k * FD + j];
#pragma unroll
    for (int i = 0; i < B8; ++i) acc[i] += lh[i * FD + k] * w;
  }
  const float alv = al[j];
  const float arv = ar[j];
#pragma unroll
  for (int i = 0; i < B8; ++i) f[(size_t)(n0 + i) * FD + j] = acc[i];
  __syncthreads();
#pragma unroll
  for (int i = 0; i < B8; ++i) lh[i * FD + j] = acc[i] * alv;
  __syncthreads();
  if (j < B8 * 2) {
    const int i = j >> 1, h = j & 1;
    const float* p = &lh[i * FD + h * 64];
    float s = 0.f;
    for (int d = 0; d < 64; ++d) s += p[d];
    el[(size_t)(n0 + i) * 2 + h] = s;
  }
  __syncthreads();
#pragma unroll
  for (int i = 0; i < B8; ++i) lh[i * FD + j] = acc[i] * arv;
  __syncthreads();
  if (j < B8 * 2) {
    const int i = j >> 1, h = j & 1;
    const float* p = &lh[i * FD + h * 64];
    float s = 0.f;
    for (int d = 0; d < 64; ++d) s += p[d];
    er[(size_t)(n0 + i) * 2 + h] = s;
  }
}

__global__ void pull_aggr(const int* __restrict__ starts,
                          const int* __restrict__ csrsrc,
                          const float* __restrict__ el,
                          const float* __restrict__ er,
                          const float* __restrict__ f,
                          const float* __restrict__ b,
                          int do_relu,
                          float* __restrict__ z) {
  const int n = blockIdx.x;
  const int j = threadIdx.x;
  const int h = j >> 6;
  const int s0 = starts[n], s1 = starts[n + 1];
  const float ern = er[(size_t)n * 2 + h];
  float acc = 0.f, den = 0.f;
  for (int p = s0; p < s1; ++p) {
    const int src = csrsrc[p];
    const float w = leaky_exp(el[(size_t)src * 2 + h] + ern);
    den += w;
    acc += w * f[(size_t)src * FD + j];
  }
  float v = acc / fmaxf(den, 1e-9f) + b[j];
  if (do_relu) v = fmaxf(v, 0.f);
  z[(size_t)n * FD + j] = v;
}

__global__ void semw_nodes(const float* __restrict__ z,
                           const float* __restrict__ aw1,
                           const float* __restrict__ ab1,
                           const float* __restrict__ aw2,
                           float* __restrict__ wv) {
  __shared__ float lz[2][FD];
  __shared__ float red[2][4][AH];
  __shared__ float wcol[2][AH];
  const int g = threadIdx.x >> 7;
  const int t = threadIdx.x & 127;
  const int pair = blockIdx.x * 2 + g;
  const int n = pair / RR;
  const int r = pair - n * RR;
  lz[g][t] = z[((size_t)r * NN + n) * FD + t];
  __syncthreads();
  const int col = t & 31;
  const int part = t >> 5;
  float acc = 0.f;
#pragma unroll
  for (int kk = 0; kk < 32; ++kk) {
    const int k = part * 32 + kk;
    acc += lz[g][k] * aw1[(size_t)k * AH + col];
  }
  red[g][part][col] = acc;
  __syncthreads();
  if (part == 0) {
    float s = red[g][0][col] + red[g][1][col] + red[g][2][col] + red[g][3][col];
    wcol[g][col] = tanhf(s + ab1[col]) * aw2[col];
  }
  __syncthreads();
  if (t == 0) {
    float w = 0.f;
#pragma unroll
    for (int c = 0; c < AH; ++c) w += wcol[g][c];
    wv[(size_t)r * NN + n] = w;
  }
}

// ---------------------------------------------------------------------------
extern "C" void kernel_launch(void* const* d_in, const int* in_sizes, int n_in,
                              void* d_out, int out_size, void* d_ws, size_t ws_size,
                              hipStream_t stream) {
  const float* x   = (const float*)d_in[0];
  const int*   edg = (const int*)d_in[1];
  const float* W1  = (const float*)d_in[2];
  const float* al1 = (const float*)d_in[3];
  const float* ar1 = (const float*)d_in[4];
  const float* b1  = (const float*)d_in[5];
  const float* W2  = (const float*)d_in[6];
  const float* al2 = (const float*)d_in[7];
  const float* ar2 = (const float*)d_in[8];
  const float* b2  = (const float*)d_in[9];
  const float* aw1 = (const float*)d_in[10];
  const float* ab1 = (const float*)d_in[11];
  const float* aw2 = (const float*)d_in[12];
  const float* bw1 = (const float*)d_in[13];
  const float* bb1 = (const float*)d_in[14];
  const float* bw2 = (const float*)d_in[15];
  float* out = (float*)d_out;

  const size_t need_big = 67200128;  // gate proven on this ws
  if (ws_size >= need_big) {
    float* S      = (float*)d_ws;                    // 16
    float* wv     = S + 16;                          // RR*NN
    float* el     = wv + (size_t)RR * NN;            // RR*NN*2
    float* er     = el + (size_t)RR * NN * 2;        // RR*NN*2
    float* z      = er + (size_t)RR * NN * 2;        // RR*NN*FD fp32
    unsigned short* fb = (unsigned short*)(z + (size_t)RR * NN * FD);  // bf16
    int*   cnt    = (int*)(fb + (size_t)RR * NN * FD);  // RR*NN
    int*   starts = cnt + RR * NN;                   // RR*NP1
    int*   cursor = starts + RR * NP1;               // RR*NP1
    int*   csrsrc = cursor + RR * NP1;               // RR*EE

    hipMemsetAsync(cnt, 0, (size_t)RR * NN * sizeof(int), stream);
    csr_count<<<(RR * EE + 255) / 256, 256, 0, stream>>>(edg, cnt);
    csr_scan<<<RR, 256, 0, stream>>>(cnt, starts, cursor);
    csr_scatter<<<(RR * EE + 255) / 256, 256, 0, stream>>>(edg, cursor, csrsrc);

    // layer 1
    gemm_all<<<RR * (NN / BN), 64, 0, stream>>>(x, W1, al1, ar1, fb, el, er);
    pull_semw<<<RR * NN, 64, 0, stream>>>(starts, csrsrc, el, er, fb, b1, 1,
                                          aw1, ab1, aw2, z, wv);
    reduce_beta<<<1, 256, 0, stream>>>(wv, S);
    combine_f32<<<(NN * FD + 255) / 256, 256, 0, stream>>>(z, S, out);  // hmid

    // layer 2
    gemm_all<<<RR * (NN / BN), 64, 0, stream>>>(out, W2, al2, ar2, fb, el, er);
    pull_semw<<<RR * NN, 64, 0, stream>>>(starts, csrsrc, el, er, fb, b2, 0,
                                          bw1, bb1, bw2, z, wv);
    reduce_beta<<<1, 256, 0, stream>>>(wv, S);
    combine_f32<<<(NN * FD + 255) / 256, 256, 0, stream>>>(z, S, out);
    return;
  }

  // ---------------- fallback: R10 CSR path (46 MB, proven) ----------------
  float* S      = (float*)d_ws;
  float* wv     = S + 16;
  float* el     = wv + (size_t)RR * NN;
  float* er     = el + (size_t)NN * 2;
  float* f      = er + (size_t)NN * 2;
  float* z      = f + (size_t)NN * FD;
  int*   cnt    = (int*)(z + (size_t)RR * NN * FD);
  int*   starts = cnt + RR * NN;
  int*   cursor = starts + RR * NP1;
  int*   csrsrc = cursor + RR * NP1;

  hipMemsetAsync(cnt, 0, (size_t)RR * NN * sizeof(int), stream);
  csr_count<<<(RR * EE + 255) / 256, 256, 0, stream>>>(edg, cnt);
  csr_scan<<<RR, 256, 0, stream>>>(cnt, starts, cursor);
  csr_scatter<<<(RR * EE + 255) / 256, 256, 0, stream>>>(edg, cursor, csrsrc);

  for (int r = 0; r < RR; ++r) {
    gemm_el_er<<<NN / 8, 128, 0, stream>>>(
        x, W1 + (size_t)r * FD * FD, al1 + r * FD, ar1 + r * FD, f, el, er);
    pull_aggr<<<NN, 128, 0, stream>>>(starts + r * NP1, csrsrc + (size_t)r * EE,
                                      el, er, f, b1 + r * FD, 1,
                                      z + (size_t)r * NN * FD);
  }
  semw_nodes<<<NN * RR / 2, 256, 0, stream>>>(z, aw1, ab1, aw2, wv);
  reduce_beta<<<1, 256, 0, stream>>>(wv, S);
  combine_f32<<<(NN * FD + 255) / 256, 256, 0, stream>>>(z, S, out);

  for (int r = 0; r < RR; ++r) {
    gemm_el_er<<<NN / 8, 128, 0, stream>>>(
        out, W2 + (size_t)r * FD * FD, al2 + r * FD, ar2 + r * FD, f, el, er);
    pull_aggr<<<NN, 128, 0, stream>>>(starts + r * NP1, csrsrc + (size_t)r * EE,
                                      el, er, f, b2 + r * FD, 0,
                                      z + (size_t)r * NN * FD);
  }
  semw_nodes<<<NN * RR / 2, 256, 0, stream>>>(z, bw1, bb1, bw2, wv);
  reduce_beta<<<1, 256, 0, stream>>>(wv, S);
  combine_f32<<<(NN * FD + 255) / 256, 256, 0, stream>>>(z, S, out);
}